// Round 8
// baseline (166.524 us; speedup 1.0000x reference)
//
#include <hip/hip_runtime.h>
#include <math.h>

#define Bn 2
#define Hn 12
#define Tn 512
#define Cn 768
#define HS 64
#define BH 24
#define MTOP 8
#define NCOMB 36
#define NEGV -1e30f

#define NX (Bn * Tn * Cn)     // 786432
#define NW (3 * Cn * Cn)      // 1769472
#define NP (Cn * Cn)          // 589824

typedef __bf16 bf16x8 __attribute__((ext_vector_type(8)));
typedef float f32x4 __attribute__((ext_vector_type(4)));
typedef unsigned long long u64;

__device__ __constant__ int C_SL0[NCOMB] = {
  0,1,2,3,4,5,6,7,
  0,0,0,0,0,0,0,
  1,1,1,1,1,1,
  2,2,2,2,2,
  3,3,3,3,
  4,4,4,
  5,5,
  6};
__device__ __constant__ int C_SL1[NCOMB] = {
  -1,-1,-1,-1,-1,-1,-1,-1,
  1,2,3,4,5,6,7,
  2,3,4,5,6,7,
  3,4,5,6,7,
  4,5,6,7,
  5,6,7,
  6,7,
  7};

__device__ __constant__ int PA[45] = {
  0,0,0,0,0,0,0,0,0,
  1,1,1,1,1,1,1,1,
  2,2,2,2,2,2,2,
  3,3,3,3,3,3,
  4,4,4,4,4,
  5,5,5,5,
  6,6,6,
  7,7,
  8};
__device__ __constant__ int PB[45] = {
  0,1,2,3,4,5,6,7,8,
  1,2,3,4,5,6,7,8,
  2,3,4,5,6,7,8,
  3,4,5,6,7,8,
  4,5,6,7,8,
  5,6,7,8,
  6,7,8,
  7,8,
  8};

// lower-triangle 8x8 tile enumeration (ti >= tj)
__device__ __constant__ int TI[36] = {
  0,1,1,2,2,2,3,3,3,3,4,4,4,4,4,5,5,5,5,5,5,6,6,6,6,6,6,6,7,7,7,7,7,7,7,7};
__device__ __constant__ int TJ[36] = {
  0,0,1,0,1,2,0,1,2,3,0,1,2,3,4,0,1,2,3,4,5,0,1,2,3,4,5,6,0,1,2,3,4,5,6,7};

__device__ __forceinline__ unsigned short bf_rne(float x) {
    unsigned u = __float_as_uint(x);
    return (unsigned short)((u + 0x7fff + ((u >> 16) & 1)) >> 16);
}
__device__ __forceinline__ float bf_f(unsigned short s) {
    return __uint_as_float(((unsigned)s) << 16);
}

// ---- DPP wave64 reductions (VALU pipe — zero LDS traffic) ----------------------------
template<int CTRL, int RM>
__device__ __forceinline__ float dpp_add_step(float x) {
    int t = __builtin_amdgcn_update_dpp(0, __float_as_int(x), CTRL, RM, 0xf, false);
    return x + __int_as_float(t);
}
template<int CTRL, int RM>
__device__ __forceinline__ float dpp_max_step(float x) {
    int t = __builtin_amdgcn_update_dpp((int)0xFF800000, __float_as_int(x), CTRL, RM, 0xf, false);
    return fmaxf(x, __int_as_float(t));
}
// full-coverage lane permute on the VALU pipe (quad_perm / row_ror) — replaces
// __shfl_xor's ds_bpermute for xor distances expressible in DPP
template<int CTRL>
__device__ __forceinline__ float dpp_permf(float x) {
    int t = __builtin_amdgcn_update_dpp(0, __float_as_int(x), CTRL, 0xf, 0xf, false);
    return __int_as_float(t);
}
__device__ __forceinline__ float wave_sum(float x) {
    x = dpp_add_step<0x111, 0xf>(x);
    x = dpp_add_step<0x112, 0xf>(x);
    x = dpp_add_step<0x114, 0xf>(x);
    x = dpp_add_step<0x118, 0xf>(x);
    x = dpp_add_step<0x142, 0xa>(x);
    x = dpp_add_step<0x143, 0xc>(x);
    return __int_as_float(__builtin_amdgcn_readlane(__float_as_int(x), 63));
}
__device__ __forceinline__ float wave_max(float x) {
    x = dpp_max_step<0x111, 0xf>(x);
    x = dpp_max_step<0x112, 0xf>(x);
    x = dpp_max_step<0x114, 0xf>(x);
    x = dpp_max_step<0x118, 0xf>(x);
    x = dpp_max_step<0x142, 0xa>(x);
    x = dpp_max_step<0x143, 0xc>(x);
    return __int_as_float(__builtin_amdgcn_readlane(__float_as_int(x), 63));
}

// ---- fused conversions, 4 elems/thread (float4 loads, 8B packed stores) --------------
__global__ __launch_bounds__(256) void conv_all(const float* __restrict__ x,
                                                const float* __restrict__ Wa,
                                                const float* __restrict__ Wp,
                                                unsigned short* __restrict__ xcat,
                                                unsigned short* __restrict__ Wcat,
                                                unsigned short* __restrict__ Wpbf) {
    const int idx = (blockIdx.x * 256 + threadIdx.x) * 4;   // all region bounds /4; Cn%4==0
    if (idx < NX) {
        int r = idx / Cn, c = idx - r * Cn;
        float4 v = *(const float4*)(x + idx);
        unsigned short h0 = bf_rne(v.x), l0 = bf_rne(v.x - bf_f(h0));
        unsigned short h1 = bf_rne(v.y), l1 = bf_rne(v.y - bf_f(h1));
        unsigned short h2 = bf_rne(v.z), l2 = bf_rne(v.z - bf_f(h2));
        unsigned short h3 = bf_rne(v.w), l3 = bf_rne(v.w - bf_f(h3));
        u64 ph = (u64)h0 | ((u64)h1 << 16) | ((u64)h2 << 32) | ((u64)h3 << 48);
        u64 pl = (u64)l0 | ((u64)l1 << 16) | ((u64)l2 << 32) | ((u64)l3 << 48);
        size_t base = (size_t)r * 2304 + c;
        *(u64*)(xcat + base)        = ph;   // [xhi | xhi | xlo]
        *(u64*)(xcat + base + 768)  = ph;
        *(u64*)(xcat + base + 1536) = pl;
    } else if (idx < NX + NW) {
        int j = idx - NX;
        int r = j / Cn, c = j - r * Cn;
        float4 v = *(const float4*)(Wa + j);
        unsigned short h0 = bf_rne(v.x), l0 = bf_rne(v.x - bf_f(h0));
        unsigned short h1 = bf_rne(v.y), l1 = bf_rne(v.y - bf_f(h1));
        unsigned short h2 = bf_rne(v.z), l2 = bf_rne(v.z - bf_f(h2));
        unsigned short h3 = bf_rne(v.w), l3 = bf_rne(v.w - bf_f(h3));
        u64 ph = (u64)h0 | ((u64)h1 << 16) | ((u64)h2 << 32) | ((u64)h3 << 48);
        u64 pl = (u64)l0 | ((u64)l1 << 16) | ((u64)l2 << 32) | ((u64)l3 << 48);
        size_t base = (size_t)r * 2304 + c;
        *(u64*)(Wcat + base)        = ph;   // [Whi | Wlo | Whi]
        *(u64*)(Wcat + base + 1536) = ph;
        *(u64*)(Wcat + base + 768)  = pl;
    } else if (idx < NX + NW + NP) {
        int j = idx - NX - NW;
        float4 v = *(const float4*)(Wp + j);
        unsigned short h0 = bf_rne(v.x), h1 = bf_rne(v.y);
        unsigned short h2 = bf_rne(v.z), h3 = bf_rne(v.w);
        *(u64*)(Wpbf + j) = (u64)h0 | ((u64)h1 << 16) | ((u64)h2 << 32) | ((u64)h3 << 48);
    }
}

// ---- global_load_lds 16B direct-to-LDS helper ----------------------------------------
__device__ __forceinline__ void gld16(const unsigned short* g, unsigned short* l) {
    __builtin_amdgcn_global_load_lds(
        (const __attribute__((address_space(1))) unsigned short*)g,
        (__attribute__((address_space(3))) unsigned short*)l, 16, 0, 0);
}

// ---- bf16 NT GEMM core, 64x64 tile: gld_lds staging, XOR-swizzled reads,
//      3-buffer LDS ring, 1 raw s_barrier + counted vmcnt(4) per 64-K chunk ------------
__device__ __forceinline__ void gemm_core(const unsigned short* __restrict__ Ag,
                                          const unsigned short* __restrict__ Bg,
                                          int Kst, int NS,
                                          unsigned short* LB,
                                          f32x4 acc[2][2]) {
    const int tid = threadIdx.x;
    const int wv = tid >> 6, lane = tid & 63;
    const int r0 = tid >> 3;                 // staging row 0..31 (round 0)
    const int sg = tid & 7;                  // staging 16B-segment 0..7
    const int gsg = sg ^ (r0 & 7);           // inverse-swizzled source segment
    const int m0w = (wv >> 1) * 32;
    const int n0w = (wv & 1) * 32;
    const int fr = lane & 15;
    const int tq = lane >> 4;                // fragment 16B-segment quarter 0..3

    const unsigned short* pa0 = Ag + (size_t)r0 * Kst + gsg * 8;
    const unsigned short* pa1 = Ag + (size_t)(r0 + 32) * Kst + gsg * 8;  // (r0+32)&7 == r0&7
    const unsigned short* pb0 = Bg + (size_t)r0 * Kst + gsg * 8;
    const unsigned short* pb1 = Bg + (size_t)(r0 + 32) * Kst + gsg * 8;

    unsigned short* lA = LB + wv * 512;          // wave-uniform DMA bases (wv*1024 B)
    unsigned short* lB = LB + 4096 + wv * 512;

    auto issue = [&](int s, int b) {
        const int cb = s * 64;                   // chunk K-offset in ushorts
        unsigned short* a  = lA + b * 8192;
        unsigned short* bb = lB + b * 8192;
        gld16(pa0 + cb, a);            // A rows 0..31
        gld16(pa1 + cb, a + 2048);     // A rows 32..63
        gld16(pb0 + cb, bb);           // B rows 0..31
        gld16(pb1 + cb, bb + 2048);    // B rows 32..63
    };

    auto compute = [&](int b) {
        const unsigned short* Ab = LB + b * 8192;
        const unsigned short* Bb = Ab + 4096;
        #pragma unroll
        for (int ks = 0; ks < 2; ++ks) {
            const int t = ks * 4 + tq;
            bf16x8 af[2], bg[2];
            #pragma unroll
            for (int mi = 0; mi < 2; ++mi) {
                const int row = m0w + 16 * mi + fr;
                af[mi] = *(const bf16x8*)(Ab + row * 64 + (t ^ (row & 7)) * 8);
            }
            #pragma unroll
            for (int ni = 0; ni < 2; ++ni) {
                const int row = n0w + 16 * ni + fr;
                bg[ni] = *(const bf16x8*)(Bb + row * 64 + (t ^ (row & 7)) * 8);
            }
            #pragma unroll
            for (int mi = 0; mi < 2; ++mi)
                #pragma unroll
                for (int ni = 0; ni < 2; ++ni)
                    acc[mi][ni] = __builtin_amdgcn_mfma_f32_16x16x32_bf16(af[mi], bg[ni], acc[mi][ni], 0, 0, 0);
        }
    };

    issue(0, 0);
    issue(1, 1);
    int b = 0;
    for (int s = 0; s < NS; ++s) {
        if (s + 1 < NS) asm volatile("s_waitcnt vmcnt(4)" ::: "memory");
        else            asm volatile("s_waitcnt vmcnt(0)" ::: "memory");
        __builtin_amdgcn_s_barrier();
        if (s + 2 < NS) {
            int bn = b + 2; if (bn >= 3) bn -= 3;
            issue(s + 2, bn);
        }
        compute(b);
        if (++b == 3) b = 0;
    }
}

// ---- qkv fused, XCD-clustered 1D grid (576 blocks, 3 blocks/CU):
// each XCD gets 3 q/k col-tiles (all 16 tm) + 1.5 v col-tiles — work-balanced.
// k-part additionally writes khat (dense fp32 K) so dpp avoids the 3-term gather -------
__global__ __launch_bounds__(256) void mfma_qkv(const unsigned short* __restrict__ xcat,
                                                const unsigned short* __restrict__ Wcat,
                                                const float* __restrict__ bias,
                                                unsigned short* __restrict__ qcat,
                                                unsigned short* __restrict__ kcat,
                                                float* __restrict__ khat,
                                                float* __restrict__ vh) {
    __shared__ __align__(16) unsigned short LB[3 * 8192];   // 49152 B
    const int xcd = blockIdx.x & 7;
    const int v = blockIdx.x >> 3;             // 0..71 within XCD
    int tmi, by;
    if (v < 48) { by = xcd * 3 + (v >> 4); tmi = v & 15; }                    // q/k
    else        { int q = xcd * 24 + (v - 48); by = 24 + (q >> 4); tmi = q & 15; }  // v
    const int tm = tmi * 64;
    const int wv = threadIdx.x >> 6, lane = threadIdx.x & 63;
    const int kq = lane >> 4, r = lane & 15;
    f32x4 acc[2][2] = {};

    if (by < 24) {
        const int tn = by * 64;
        gemm_core(xcat + (size_t)tm * 2304, Wcat + (size_t)tn * 2304, 2304, 36, LB, acc);
        const int part = tn / Cn;          // 0=q, 1=k
        #pragma unroll
        for (int mi = 0; mi < 2; ++mi) {
            #pragma unroll
            for (int ni = 0; ni < 2; ++ni) {
                #pragma unroll
                for (int rr = 0; rr < 4; ++rr) {
                    int mm = tm + (wv >> 1) * 32 + mi * 16 + kq * 4 + rr;
                    int nn = tn + (wv & 1) * 32 + ni * 16 + r;
                    float val = acc[mi][ni][rr] + bias[nn];
                    int bb = mm >> 9, t = mm & 511;
                    int c = nn - part * Cn;
                    int h = c >> 6, d = c & 63;
                    int bh = bb * Hn + h;
                    unsigned short s1 = bf_rne(val);
                    float r1 = val - bf_f(s1);
                    unsigned short s2 = bf_rne(r1);
                    unsigned short s3 = bf_rne(r1 - bf_f(s2));
                    size_t base = ((size_t)bh * Tn + t) * 384 + d;
                    if (part == 0) {   // qcat = [q1|q1|q2|q1|q3|q2]
                        qcat[base]       = s1;
                        qcat[base + 64]  = s1;
                        qcat[base + 192] = s1;
                        qcat[base + 128] = s2;
                        qcat[base + 320] = s2;
                        qcat[base + 256] = s3;
                    } else {           // kcat = [k1|k2|k1|k3|k1|k2]
                        kcat[base]       = s1;
                        kcat[base + 128] = s1;
                        kcat[base + 256] = s1;
                        kcat[base + 64]  = s2;
                        kcat[base + 320] = s2;
                        kcat[base + 192] = s3;
                        khat[((size_t)bh * Tn + t) * HS + d] = val;  // dense fp32 K
                    }
                }
            }
        }
    } else {
        // v: single-term bf16 (xhi @ Wvhi^T), K extent 768 within stride-2304 rows
        const int hvi = by - 24;           // head-col tile 0..11
        const int cv = hvi * 64;
        gemm_core(xcat + (size_t)tm * 2304,
                  Wcat + (size_t)(1536 + cv) * 2304, 2304, 12, LB, acc);
        #pragma unroll
        for (int mi = 0; mi < 2; ++mi) {
            #pragma unroll
            for (int ni = 0; ni < 2; ++ni) {
                #pragma unroll
                for (int rr = 0; rr < 4; ++rr) {
                    int mm = tm + (wv >> 1) * 32 + mi * 16 + kq * 4 + rr;
                    int nloc = (wv & 1) * 32 + ni * 16 + r;      // 0..63 == d
                    float val = acc[mi][ni][rr] + bias[1536 + cv + nloc];
                    int bb = mm >> 9, t = mm & 511;
                    int bh = bb * Hn + hvi;
                    vh[((size_t)bh * Tn + t) * HS + nloc] = val;
                }
            }
        }
    }
}

// ---- sim, XCD-clustered 1D grid (864 blocks): each XCD owns 3 bh -------------------
__global__ __launch_bounds__(256) void mfma_sim(const unsigned short* __restrict__ qcat,
                                                const unsigned short* __restrict__ kcat,
                                                float* __restrict__ S) {
    __shared__ __align__(16) unsigned short LB[3 * 8192];
    const int xcd = blockIdx.x & 7;
    const int v = blockIdx.x >> 3;             // 0..107
    const int bh = xcd * 3 + v / 36;
    const int tile = v % 36;
    const int ti = TI[tile], tj = TJ[tile];
    f32x4 acc[2][2] = {};
    gemm_core(qcat + ((size_t)bh * Tn + ti * 64) * 384,
              kcat + ((size_t)bh * Tn + tj * 64) * 384, 384, 6, LB, acc);

    const int wv = threadIdx.x >> 6, lane = threadIdx.x & 63;
    const int kq = lane >> 4, r = lane & 15;
    float* Sp = S + (size_t)bh * 147456 + (size_t)(ti * (ti + 1) / 2 + tj) * 4096;
    #pragma unroll
    for (int mi = 0; mi < 2; ++mi)
        #pragma unroll
        for (int ni = 0; ni < 2; ++ni)
            #pragma unroll
            for (int rr = 0; rr < 4; ++rr) {
                int ml = (wv >> 1) * 32 + mi * 16 + kq * 4 + rr;
                int nl = (wv & 1) * 32 + ni * 16 + r;
                Sp[ml * 64 + nl] = acc[mi][ni][rr];
            }
}

// ---- proj, XCD-clustered 1D grid (192 blocks) ----------------------------------------
__global__ __launch_bounds__(256) void mfma_proj(const unsigned short* __restrict__ Abf,
                                                 const unsigned short* __restrict__ Bbf,
                                                 const float* __restrict__ bias,
                                                 float* __restrict__ outp) {
    __shared__ __align__(16) unsigned short LB[3 * 8192];
    const int xcd = blockIdx.x & 7;
    const int q = xcd * 24 + (blockIdx.x >> 3); // 0..191
    const int tm = (q & 15) * 64;
    const int tn = (q >> 4) * 64;
    f32x4 acc[2][2] = {};
    gemm_core(Abf + (size_t)tm * Cn, Bbf + (size_t)tn * Cn, Cn, 12, LB, acc);

    const int wv = threadIdx.x >> 6, lane = threadIdx.x & 63;
    const int kq = lane >> 4, r = lane & 15;
    #pragma unroll
    for (int mi = 0; mi < 2; ++mi)
        #pragma unroll
        for (int ni = 0; ni < 2; ++ni)
            #pragma unroll
            for (int rr = 0; rr < 4; ++rr) {
                int mm = tm + (wv >> 1) * 32 + mi * 16 + kq * 4 + rr;
                int nn = tn + (wv & 1) * 32 + ni * 16 + r;
                outp[(size_t)mm * Cn + nn] = acc[mi][ni][rr] + bias[nn];
            }
}

// float compare-exchange, descending (larger to lower index)
#define CEF(arr, ia, ib) { \
    float _a = arr[ia], _b = arr[ib]; \
    arr[ia] = fmaxf(_a, _b); arr[ib] = fminf(_a, _b); }

// one bitonic top-8 merge step with a caller-provided lane-permute
#define MERGE_WITH(PERM)                                              \
    {                                                                 \
        float pk[8];                                                  \
        _Pragma("unroll")                                             \
        for (int r = 0; r < 8; ++r) pk[r] = PERM(key[r]);             \
        float t[8];                                                   \
        _Pragma("unroll")                                             \
        for (int r = 0; r < 8; ++r) t[r] = fmaxf(key[r], pk[7 - r]);  \
        CEF(t,0,4) CEF(t,1,5) CEF(t,2,6) CEF(t,3,7)                   \
        CEF(t,0,2) CEF(t,1,3) CEF(t,4,6) CEF(t,5,7)                   \
        CEF(t,0,1) CEF(t,2,3) CEF(t,4,5) CEF(t,6,7)                   \
        _Pragma("unroll")                                             \
        for (int r = 0; r < 8; ++r) key[r] = t[r];                    \
    }

#define SHFLX4(x)  __shfl_xor((x), 4, 64)
#define SHFLX16(x) __shfl_xor((x), 16, 64)
#define SHFLX32(x) __shfl_xor((x), 32, 64)

// ---- DPP selection: ONE token per wave; XCD-clustered; fast-path index recovery;
// K rows staged from dense fp32 khat; merge stages xor1/2/8 on VALU via DPP ------------
__global__ __launch_bounds__(256, 8) void dpp_kernel(const float* __restrict__ S,
                                                     const float* __restrict__ khat,
                                                     const float* __restrict__ vh,
                                                     unsigned short* __restrict__ yb) {
    const int xcd = blockIdx.x & 7;
    const int vb = blockIdx.x >> 3;            // 0..383
    const int bh = xcd * 3 + (vb >> 7);
    const int iblk = vb & 127;
    const int w = threadIdx.x >> 6;
    const int lane = threadIdx.x & 63;
    const int i = iblk * 4 + w;                // token for this wave

    __shared__ float KshW[4][9][68];   //  9792 B
    __shared__ float VshW[4][9][64];   //  9216 B
    __shared__ float Gsh[4][81];       //  1296 B
    __shared__ float qdsh[4][9];       //   144 B  -> 20448 B total (8 blocks/CU)
    const float* Sbh = S + (size_t)bh * 147456;
    const float* kh = khat + (size_t)bh * Tn * HS;
    const float* vbase = vh + (size_t)bh * Tn * HS;

    const int t8 = i >> 6;
    const int tribase = t8 * (t8 + 1) / 2;
    const int rloc = (i & 63) * 64;

    float sv[8];
    #pragma unroll
    for (int rr = 0; rr < 8; ++rr) {
        sv[rr] = -INFINITY;
        if (rr <= t8) {
            int j = rr * 64 + lane;
            float s = Sbh[(size_t)(tribase + rr) * 4096 + rloc + lane];
            sv[rr] = (j <= i) ? s : -INFINITY;
        }
    }
    // qd0 = S[i][i] loaded directly (same addr all lanes -> broadcast)
    const float qd0 = Sbh[(size_t)(tribase + t8) * 4096 + rloc + (i & 63)];

    // ---- top-8 VALUES via sorted merge (32-bit, 1 permute per key) -------------------
    float key[8];
    #pragma unroll
    for (int r = 0; r < 8; ++r) key[r] = sv[r];

    // per-lane Batcher odd-even mergesort 8 (descending) — pure VALU
    CEF(key,0,1) CEF(key,2,3) CEF(key,4,5) CEF(key,6,7)
    CEF(key,0,2) CEF(key,1,3) CEF(key,4,6) CEF(key,5,7)
    CEF(key,1,2) CEF(key,5,6)
    CEF(key,0,4) CEF(key,1,5) CEF(key,2,6) CEF(key,3,7)
    CEF(key,2,4) CEF(key,3,5)
    CEF(key,1,2) CEF(key,3,4) CEF(key,5,6)

    // 6 butterfly merge stages: top-8 of self U partner.
    MERGE_WITH(dpp_permf<0xB1>)     // off 1
    MERGE_WITH(dpp_permf<0x4E>)     // off 2
    MERGE_WITH(SHFLX4)              // off 4
    MERGE_WITH(dpp_permf<0x128>)    // off 8
    MERGE_WITH(SHFLX16)             // off 16
    MERGE_WITH(SHFLX32)             // off 32
    // all lanes now hold identical sorted top-8 values key[0..7]

    // ---- index recovery: 8 independent ballot-selects per position -------------------
    int topi[8];
    #pragma unroll
    for (int p = 0; p < 8; ++p) {
        float v = key[p];
        int idx = i;
        #pragma unroll
        for (int r = 7; r >= 0; --r) {             // descending: lowest r written last
            unsigned long long m = __ballot(sv[r] == v);
            if (m != 0ull) idx = r * 64 + __builtin_ctzll(m);
        }
        topi[p] = idx;
    }

    // stage K/V rows (ctx = w; single-wave produce/consume, no barrier needed)
    #pragma unroll
    for (int a = 0; a < 9; ++a) {
        int t = (a == 0) ? i : topi[a - 1];
        KshW[w][a][lane] = kh[(size_t)t * HS + lane];
        VshW[w][a][lane] = vbase[(size_t)t * HS + lane];
    }
    if (lane < 9) {
        float val = qd0;
        #pragma unroll
        for (int p = 0; p < 8; ++p) if (lane == p + 1) val = key[p];
        qdsh[w][lane] = val;
    }

    // gram (lanes 0..44)
    if (lane < 45) {
        const int a = PA[lane], b = PB[lane];
        const float4* rka = (const float4*)&KshW[w][a][0];
        const float4* rkb = (const float4*)&KshW[w][b][0];
        float acc = 0.f;
        #pragma unroll
        for (int t = 0; t < 16; ++t) {
            float4 fa = rka[t], fb = rkb[t];
            acc += fa.x * fb.x; acc += fa.y * fb.y;
            acc += fa.z * fb.z; acc += fa.w * fb.w;
        }
        Gsh[w][a * 9 + b] = acc;
        Gsh[w][b * 9 + a] = acc;
    }

    // combos (lanes 0..35)
    const int sl0c = (lane < NCOMB) ? C_SL0[lane] : -1;
    const int sl1c = (lane < NCOMB) ? C_SL1[lane] : -1;
    float score = -INFINITY;
    int ca = 0, cb = 0, sdim = 1;
    {
        const int n_cand = (i + 1 < MTOP) ? (i + 1) : MTOP;
        int vmask = 0;
        #pragma unroll
        for (int s = 0; s < MTOP; ++s)
            if (s < n_cand && topi[s] != i) vmask |= (1 << s);

        if (lane < NCOMB) {
            sdim = (sl1c < 0) ? 1 : 2;
            ca = sl0c + 1;
            cb = (sl1c < 0) ? 0 : sl1c + 1;
            bool valid = ((vmask >> sl0c) & 1);
            if (sdim == 2) valid = valid && ((vmask >> sl1c) & 1);
            float G00 = Gsh[w][0];
            float Gaa = Gsh[w][ca * 9 + ca];
            float G0a = Gsh[w][ca];
            float det;
            if (sdim == 1) {
                det = G00 * Gaa - G0a * G0a;
            } else {
                float G0b = Gsh[w][cb];
                float Gab = Gsh[w][ca * 9 + cb];
                float Gbb = Gsh[w][cb * 9 + cb];
                det = G00 * (Gaa * Gbb - Gab * Gab)
                    - G0a * (G0a * Gbb - Gab * G0b)
                    + G0b * (G0a * Gab - Gaa * G0b);
            }
            score = valid ? (logf(det + 1e-6f) / (float)(sdim + 1)) : NEGV;
        }
    }

    // softmax over scores: DPP reductions (VALU pipe)
    const float mxv = wave_max(score);
    const float ee = (lane < NCOMB) ? expf(score - mxv) : 0.f;
    const float sumv = wave_sum(ee);

    // per-lane prob-folded attention weights
    float pwx = 0.f, pwy = 0.f, pwz = 0.f;
    if (lane < NCOMB) {
        float prob = ee / sumv;
        float d0 = qdsh[w][0]  * 0.125f;
        float d1 = qdsh[w][ca] * 0.125f;
        float d2 = (sdim == 2) ? qdsh[w][cb] * 0.125f : -INFINITY;
        float m2 = fmaxf(fmaxf(d0, d1), d2);
        float e0 = expf(d0 - m2), e1 = expf(d1 - m2);
        float e2 = (sdim == 2) ? expf(d2 - m2) : 0.f;
        float inv = prob / (e0 + e1 + e2);
        pwx = e0 * inv; pwy = e1 * inv; pwz = e2 * inv;
    }

    // coefficient collapse via DPP sums: y = c0*V0 + sum_s cs[s]*V[s+1]
    const float c0 = wave_sum(pwx);
    float cs[8];
    #pragma unroll
    for (int s = 0; s < 8; ++s) {
        float contrib = ((sl0c == s) ? pwy : 0.f) + ((sl1c == s) ? pwz : 0.f);
        cs[s] = wave_sum(contrib);
    }

    // y (9 LDS b32 reads)
    {
        const bool hasValid = (mxv > -1e29f);
        const float v0 = VshW[w][0][lane];
        float y = v0;
        if (hasValid) {
            y = c0 * v0;
            #pragma unroll
            for (int s = 0; s < 8; ++s)
                y += cs[s] * VshW[w][s + 1][lane];
        }
        const int bb = bh / Hn, h = bh % Hn;
        yb[((size_t)(bb * Tn + i)) * Cn + h * HS + lane] = bf_rne(y);
    }
}

extern "C" void kernel_launch(void* const* d_in, const int* in_sizes, int n_in,
                              void* d_out, int out_size, void* d_ws, size_t ws_size,
                              hipStream_t stream) {
    const float* x      = (const float*)d_in[0];
    const float* W_attn = (const float*)d_in[1];
    const float* b_attn = (const float*)d_in[2];
    const float* W_proj = (const float*)d_in[3];
    const float* b_proj = (const float*)d_in[4];
    float* out = (float*)d_out;

    char* ws = (char*)d_ws;
    float* vh            = (float*)(ws);                          //  0        3 MB
    unsigned short* qcat = (unsigned short*)(ws + 3145728);       //  3 MB     9 MB
    unsigned short* kcat = (unsigned short*)(ws + 12582912);      // 12 MB     9 MB
    unsigned short* xcat = (unsigned short*)(ws + 22020096);      // 21 MB     4.5 MB (dead after qkv)
    unsigned short* Wcat = (unsigned short*)(ws + 26738688);      // 25.5 MB  10.125 MB (dead after qkv)
    float* S             = (float*)(ws + 26738688);               // overlays Wcat, 13.5 MB
    unsigned short* ybf  = xcat;                                  // overlays xcat after qkv
    unsigned short* Wpbf = (unsigned short*)(ws + 40894464);      // 39 MB     1.125 MB
    float* khat          = (float*)(ws + 44040192);               // 42 MB     3 MB -> 45 MB total

    // ---- r7 TIMING PROBE: double-launch every idempotent kernel EXCEPT dpp.
    // dur - 127.3 = t_conv + t_qkv + t_sim + t_proj (warm). With t_dpp=23.3 known,
    // the full per-kernel decomposition of the 127 µs follows. All launches are pure
    // functions of already-final buffers (Wcat dead before sim's S overlay; ybf final
    // before proj), so outputs are bit-identical.

    // 1) all conversions in one launch (4 elems/thread) — x2 probe
    conv_all<<<dim3((NX + NW + NP) / 4 / 256), 256, 0, stream>>>(
        x, W_attn, W_proj, xcat, Wcat, Wpbf);
    conv_all<<<dim3((NX + NW + NP) / 4 / 256), 256, 0, stream>>>(
        x, W_attn, W_proj, xcat, Wcat, Wpbf);

    // 2) fused qkv, 64x64 tiles, XCD-clustered — x2 probe
    mfma_qkv<<<dim3(576), 256, 0, stream>>>(xcat, Wcat, b_attn, qcat, kcat, khat, vh);
    mfma_qkv<<<dim3(576), 256, 0, stream>>>(xcat, Wcat, b_attn, qcat, kcat, khat, vh);

    // 3) S = qcat @ kcat^T, XCD-clustered — x2 probe
    mfma_sim<<<dim3(864), 256, 0, stream>>>(qcat, kcat, S);
    mfma_sim<<<dim3(864), 256, 0, stream>>>(qcat, kcat, S);

    // 4) dpp — single (t_dpp already measured = 23.3 µs)
    dpp_kernel<<<dim3(3072), 256, 0, stream>>>(S, khat, vh, ybf);

    // 5) out = y @ Wp^T + bias — x2 probe
    mfma_proj<<<dim3(192), 256, 0, stream>>>(ybf, Wpbf, b_proj, out);
    mfma_proj<<<dim3(192), 256, 0, stream>>>(ybf, Wpbf, b_proj, out);
}

// Round 10
// 126.629 us; speedup vs baseline: 1.3150x; 1.3150x over previous
//
#include <hip/hip_runtime.h>
#include <math.h>

#define Bn 2
#define Hn 12
#define Tn 512
#define Cn 768
#define HS 64
#define BH 24
#define MTOP 8
#define NCOMB 36
#define NEGV -1e30f

#define NX (Bn * Tn * Cn)     // 786432
#define NW (3 * Cn * Cn)      // 1769472
#define NP (Cn * Cn)          // 589824

typedef __bf16 bf16x8 __attribute__((ext_vector_type(8)));
typedef float f32x4 __attribute__((ext_vector_type(4)));
typedef unsigned long long u64;

__device__ __constant__ int C_SL0[NCOMB] = {
  0,1,2,3,4,5,6,7,
  0,0,0,0,0,0,0,
  1,1,1,1,1,1,
  2,2,2,2,2,
  3,3,3,3,
  4,4,4,
  5,5,
  6};
__device__ __constant__ int C_SL1[NCOMB] = {
  -1,-1,-1,-1,-1,-1,-1,-1,
  1,2,3,4,5,6,7,
  2,3,4,5,6,7,
  3,4,5,6,7,
  4,5,6,7,
  5,6,7,
  6,7,
  7};

__device__ __constant__ int PA[45] = {
  0,0,0,0,0,0,0,0,0,
  1,1,1,1,1,1,1,1,
  2,2,2,2,2,2,2,
  3,3,3,3,3,3,
  4,4,4,4,4,
  5,5,5,5,
  6,6,6,
  7,7,
  8};
__device__ __constant__ int PB[45] = {
  0,1,2,3,4,5,6,7,8,
  1,2,3,4,5,6,7,8,
  2,3,4,5,6,7,8,
  3,4,5,6,7,8,
  4,5,6,7,8,
  5,6,7,8,
  6,7,8,
  7,8,
  8};

// lower-triangle 8x8 tile enumeration (ti >= tj)
__device__ __constant__ int TI[36] = {
  0,1,1,2,2,2,3,3,3,3,4,4,4,4,4,5,5,5,5,5,5,6,6,6,6,6,6,6,7,7,7,7,7,7,7,7};
__device__ __constant__ int TJ[36] = {
  0,0,1,0,1,2,0,1,2,3,0,1,2,3,4,0,1,2,3,4,5,0,1,2,3,4,5,6,0,1,2,3,4,5,6,7};

__device__ __forceinline__ unsigned short bf_rne(float x) {
    unsigned u = __float_as_uint(x);
    return (unsigned short)((u + 0x7fff + ((u >> 16) & 1)) >> 16);
}
__device__ __forceinline__ float bf_f(unsigned short s) {
    return __uint_as_float(((unsigned)s) << 16);
}

// ---- DPP wave64 reductions (VALU pipe — zero LDS traffic) ----------------------------
template<int CTRL, int RM>
__device__ __forceinline__ float dpp_add_step(float x) {
    int t = __builtin_amdgcn_update_dpp(0, __float_as_int(x), CTRL, RM, 0xf, false);
    return x + __int_as_float(t);
}
template<int CTRL, int RM>
__device__ __forceinline__ float dpp_max_step(float x) {
    int t = __builtin_amdgcn_update_dpp((int)0xFF800000, __float_as_int(x), CTRL, RM, 0xf, false);
    return fmaxf(x, __int_as_float(t));
}
template<int CTRL, int RM>
__device__ __forceinline__ int dpp_min_i32_step(int x) {
    int t = __builtin_amdgcn_update_dpp(0x7fffffff, x, CTRL, RM, 0xf, false);
    return (x < t) ? x : t;
}
__device__ __forceinline__ float wave_sum(float x) {
    x = dpp_add_step<0x111, 0xf>(x);
    x = dpp_add_step<0x112, 0xf>(x);
    x = dpp_add_step<0x114, 0xf>(x);
    x = dpp_add_step<0x118, 0xf>(x);
    x = dpp_add_step<0x142, 0xa>(x);
    x = dpp_add_step<0x143, 0xc>(x);
    return __int_as_float(__builtin_amdgcn_readlane(__float_as_int(x), 63));
}
__device__ __forceinline__ float wave_max(float x) {
    x = dpp_max_step<0x111, 0xf>(x);
    x = dpp_max_step<0x112, 0xf>(x);
    x = dpp_max_step<0x114, 0xf>(x);
    x = dpp_max_step<0x118, 0xf>(x);
    x = dpp_max_step<0x142, 0xa>(x);
    x = dpp_max_step<0x143, 0xc>(x);
    return __int_as_float(__builtin_amdgcn_readlane(__float_as_int(x), 63));
}
__device__ __forceinline__ int wave_min_i32(int x) {
    x = dpp_min_i32_step<0x111, 0xf>(x);
    x = dpp_min_i32_step<0x112, 0xf>(x);
    x = dpp_min_i32_step<0x114, 0xf>(x);
    x = dpp_min_i32_step<0x118, 0xf>(x);
    x = dpp_min_i32_step<0x142, 0xa>(x);
    x = dpp_min_i32_step<0x143, 0xc>(x);
    return __builtin_amdgcn_readlane(x, 63);
}

// ---- fused conversions, 4 elems/thread (float4 loads, 8B packed stores) --------------
__global__ __launch_bounds__(256) void conv_all(const float* __restrict__ x,
                                                const float* __restrict__ Wa,
                                                const float* __restrict__ Wp,
                                                unsigned short* __restrict__ xcat,
                                                unsigned short* __restrict__ Wcat,
                                                unsigned short* __restrict__ Wpbf) {
    const int idx = (blockIdx.x * 256 + threadIdx.x) * 4;   // all region bounds /4; Cn%4==0
    if (idx < NX) {
        int r = idx / Cn, c = idx - r * Cn;
        float4 v = *(const float4*)(x + idx);
        unsigned short h0 = bf_rne(v.x), l0 = bf_rne(v.x - bf_f(h0));
        unsigned short h1 = bf_rne(v.y), l1 = bf_rne(v.y - bf_f(h1));
        unsigned short h2 = bf_rne(v.z), l2 = bf_rne(v.z - bf_f(h2));
        unsigned short h3 = bf_rne(v.w), l3 = bf_rne(v.w - bf_f(h3));
        u64 ph = (u64)h0 | ((u64)h1 << 16) | ((u64)h2 << 32) | ((u64)h3 << 48);
        u64 pl = (u64)l0 | ((u64)l1 << 16) | ((u64)l2 << 32) | ((u64)l3 << 48);
        size_t base = (size_t)r * 2304 + c;
        *(u64*)(xcat + base)        = ph;   // [xhi | xhi | xlo]
        *(u64*)(xcat + base + 768)  = ph;
        *(u64*)(xcat + base + 1536) = pl;
    } else if (idx < NX + NW) {
        int j = idx - NX;
        int r = j / Cn, c = j - r * Cn;
        float4 v = *(const float4*)(Wa + j);
        unsigned short h0 = bf_rne(v.x), l0 = bf_rne(v.x - bf_f(h0));
        unsigned short h1 = bf_rne(v.y), l1 = bf_rne(v.y - bf_f(h1));
        unsigned short h2 = bf_rne(v.z), l2 = bf_rne(v.z - bf_f(h2));
        unsigned short h3 = bf_rne(v.w), l3 = bf_rne(v.w - bf_f(h3));
        u64 ph = (u64)h0 | ((u64)h1 << 16) | ((u64)h2 << 32) | ((u64)h3 << 48);
        u64 pl = (u64)l0 | ((u64)l1 << 16) | ((u64)l2 << 32) | ((u64)l3 << 48);
        size_t base = (size_t)r * 2304 + c;
        *(u64*)(Wcat + base)        = ph;   // [Whi | Wlo | Whi]
        *(u64*)(Wcat + base + 1536) = ph;
        *(u64*)(Wcat + base + 768)  = pl;
    } else if (idx < NX + NW + NP) {
        int j = idx - NX - NW;
        float4 v = *(const float4*)(Wp + j);
        unsigned short h0 = bf_rne(v.x), h1 = bf_rne(v.y);
        unsigned short h2 = bf_rne(v.z), h3 = bf_rne(v.w);
        *(u64*)(Wpbf + j) = (u64)h0 | ((u64)h1 << 16) | ((u64)h2 << 32) | ((u64)h3 << 48);
    }
}

// ---- global_load_lds 16B direct-to-LDS helper ----------------------------------------
__device__ __forceinline__ void gld16(const unsigned short* g, unsigned short* l) {
    __builtin_amdgcn_global_load_lds(
        (const __attribute__((address_space(1))) unsigned short*)g,
        (__attribute__((address_space(3))) unsigned short*)l, 16, 0, 0);
}

// ---- bf16 NT GEMM core, 64x64 tile: gld_lds staging, XOR-swizzled reads,
//      3-buffer LDS ring, 1 raw s_barrier + counted vmcnt(4) per 64-K chunk ------------
__device__ __forceinline__ void gemm_core(const unsigned short* __restrict__ Ag,
                                          const unsigned short* __restrict__ Bg,
                                          int Kst, int NS,
                                          unsigned short* LB,
                                          f32x4 acc[2][2]) {
    const int tid = threadIdx.x;
    const int wv = tid >> 6, lane = tid & 63;
    const int r0 = tid >> 3;                 // staging row 0..31 (round 0)
    const int sg = tid & 7;                  // staging 16B-segment 0..7
    const int gsg = sg ^ (r0 & 7);           // inverse-swizzled source segment
    const int m0w = (wv >> 1) * 32;
    const int n0w = (wv & 1) * 32;
    const int fr = lane & 15;
    const int tq = lane >> 4;                // fragment 16B-segment quarter 0..3

    const unsigned short* pa0 = Ag + (size_t)r0 * Kst + gsg * 8;
    const unsigned short* pa1 = Ag + (size_t)(r0 + 32) * Kst + gsg * 8;  // (r0+32)&7 == r0&7
    const unsigned short* pb0 = Bg + (size_t)r0 * Kst + gsg * 8;
    const unsigned short* pb1 = Bg + (size_t)(r0 + 32) * Kst + gsg * 8;

    unsigned short* lA = LB + wv * 512;          // wave-uniform DMA bases (wv*1024 B)
    unsigned short* lB = LB + 4096 + wv * 512;

    auto issue = [&](int s, int b) {
        const int cb = s * 64;                   // chunk K-offset in ushorts
        unsigned short* a  = lA + b * 8192;
        unsigned short* bb = lB + b * 8192;
        gld16(pa0 + cb, a);            // A rows 0..31
        gld16(pa1 + cb, a + 2048);     // A rows 32..63
        gld16(pb0 + cb, bb);           // B rows 0..31
        gld16(pb1 + cb, bb + 2048);    // B rows 32..63
    };

    auto compute = [&](int b) {
        const unsigned short* Ab = LB + b * 8192;
        const unsigned short* Bb = Ab + 4096;
        #pragma unroll
        for (int ks = 0; ks < 2; ++ks) {
            const int t = ks * 4 + tq;
            bf16x8 af[2], bg[2];
            #pragma unroll
            for (int mi = 0; mi < 2; ++mi) {
                const int row = m0w + 16 * mi + fr;
                af[mi] = *(const bf16x8*)(Ab + row * 64 + (t ^ (row & 7)) * 8);
            }
            #pragma unroll
            for (int ni = 0; ni < 2; ++ni) {
                const int row = n0w + 16 * ni + fr;
                bg[ni] = *(const bf16x8*)(Bb + row * 64 + (t ^ (row & 7)) * 8);
            }
            #pragma unroll
            for (int mi = 0; mi < 2; ++mi)
                #pragma unroll
                for (int ni = 0; ni < 2; ++ni)
                    acc[mi][ni] = __builtin_amdgcn_mfma_f32_16x16x32_bf16(af[mi], bg[ni], acc[mi][ni], 0, 0, 0);
        }
    };

    issue(0, 0);
    issue(1, 1);
    int b = 0;
    for (int s = 0; s < NS; ++s) {
        if (s + 1 < NS) asm volatile("s_waitcnt vmcnt(4)" ::: "memory");
        else            asm volatile("s_waitcnt vmcnt(0)" ::: "memory");
        __builtin_amdgcn_s_barrier();
        if (s + 2 < NS) {
            int bn = b + 2; if (bn >= 3) bn -= 3;
            issue(s + 2, bn);
        }
        compute(b);
        if (++b == 3) b = 0;
    }
}

// ---- qkv fused, XCD-clustered 1D grid (576 blocks, 3 blocks/CU):
// each XCD gets 3 q/k col-tiles (all 16 tm) + 1.5 v col-tiles — work-balanced.
// k-part additionally writes khat (dense fp32 K) so dpp avoids the 3-term gather -------
__global__ __launch_bounds__(256) void mfma_qkv(const unsigned short* __restrict__ xcat,
                                                const unsigned short* __restrict__ Wcat,
                                                const float* __restrict__ bias,
                                                unsigned short* __restrict__ qcat,
                                                unsigned short* __restrict__ kcat,
                                                float* __restrict__ khat,
                                                float* __restrict__ vh) {
    __shared__ __align__(16) unsigned short LB[3 * 8192];   // 49152 B
    const int xcd = blockIdx.x & 7;
    const int v = blockIdx.x >> 3;             // 0..71 within XCD
    int tmi, by;
    if (v < 48) { by = xcd * 3 + (v >> 4); tmi = v & 15; }                    // q/k
    else        { int q = xcd * 24 + (v - 48); by = 24 + (q >> 4); tmi = q & 15; }  // v
    const int tm = tmi * 64;
    const int wv = threadIdx.x >> 6, lane = threadIdx.x & 63;
    const int kq = lane >> 4, r = lane & 15;
    f32x4 acc[2][2] = {};

    if (by < 24) {
        const int tn = by * 64;
        gemm_core(xcat + (size_t)tm * 2304, Wcat + (size_t)tn * 2304, 2304, 36, LB, acc);
        const int part = tn / Cn;          // 0=q, 1=k
        #pragma unroll
        for (int mi = 0; mi < 2; ++mi) {
            #pragma unroll
            for (int ni = 0; ni < 2; ++ni) {
                #pragma unroll
                for (int rr = 0; rr < 4; ++rr) {
                    int mm = tm + (wv >> 1) * 32 + mi * 16 + kq * 4 + rr;
                    int nn = tn + (wv & 1) * 32 + ni * 16 + r;
                    float val = acc[mi][ni][rr] + bias[nn];
                    int bb = mm >> 9, t = mm & 511;
                    int c = nn - part * Cn;
                    int h = c >> 6, d = c & 63;
                    int bh = bb * Hn + h;
                    unsigned short s1 = bf_rne(val);
                    float r1 = val - bf_f(s1);
                    unsigned short s2 = bf_rne(r1);
                    unsigned short s3 = bf_rne(r1 - bf_f(s2));
                    size_t base = ((size_t)bh * Tn + t) * 384 + d;
                    if (part == 0) {   // qcat = [q1|q1|q2|q1|q3|q2]
                        qcat[base]       = s1;
                        qcat[base + 64]  = s1;
                        qcat[base + 192] = s1;
                        qcat[base + 128] = s2;
                        qcat[base + 320] = s2;
                        qcat[base + 256] = s3;
                    } else {           // kcat = [k1|k2|k1|k3|k1|k2]
                        kcat[base]       = s1;
                        kcat[base + 128] = s1;
                        kcat[base + 256] = s1;
                        kcat[base + 64]  = s2;
                        kcat[base + 320] = s2;
                        kcat[base + 192] = s3;
                        khat[((size_t)bh * Tn + t) * HS + d] = val;  // dense fp32 K
                    }
                }
            }
        }
    } else {
        // v: single-term bf16 (xhi @ Wvhi^T), K extent 768 within stride-2304 rows
        const int hvi = by - 24;           // head-col tile 0..11
        const int cv = hvi * 64;
        gemm_core(xcat + (size_t)tm * 2304,
                  Wcat + (size_t)(1536 + cv) * 2304, 2304, 12, LB, acc);
        #pragma unroll
        for (int mi = 0; mi < 2; ++mi) {
            #pragma unroll
            for (int ni = 0; ni < 2; ++ni) {
                #pragma unroll
                for (int rr = 0; rr < 4; ++rr) {
                    int mm = tm + (wv >> 1) * 32 + mi * 16 + kq * 4 + rr;
                    int nloc = (wv & 1) * 32 + ni * 16 + r;      // 0..63 == d
                    float val = acc[mi][ni][rr] + bias[1536 + cv + nloc];
                    int bb = mm >> 9, t = mm & 511;
                    int bh = bb * Hn + hvi;
                    vh[((size_t)bh * Tn + t) * HS + nloc] = val;
                }
            }
        }
    }
}

// ---- sim, XCD-clustered 1D grid (864 blocks): each XCD owns 3 bh -------------------
__global__ __launch_bounds__(256) void mfma_sim(const unsigned short* __restrict__ qcat,
                                                const unsigned short* __restrict__ kcat,
                                                float* __restrict__ S) {
    __shared__ __align__(16) unsigned short LB[3 * 8192];
    const int xcd = blockIdx.x & 7;
    const int v = blockIdx.x >> 3;             // 0..107
    const int bh = xcd * 3 + v / 36;
    const int tile = v % 36;
    const int ti = TI[tile], tj = TJ[tile];
    f32x4 acc[2][2] = {};
    gemm_core(qcat + ((size_t)bh * Tn + ti * 64) * 384,
              kcat + ((size_t)bh * Tn + tj * 64) * 384, 384, 6, LB, acc);

    const int wv = threadIdx.x >> 6, lane = threadIdx.x & 63;
    const int kq = lane >> 4, r = lane & 15;
    float* Sp = S + (size_t)bh * 147456 + (size_t)(ti * (ti + 1) / 2 + tj) * 4096;
    #pragma unroll
    for (int mi = 0; mi < 2; ++mi)
        #pragma unroll
        for (int ni = 0; ni < 2; ++ni)
            #pragma unroll
            for (int rr = 0; rr < 4; ++rr) {
                int ml = (wv >> 1) * 32 + mi * 16 + kq * 4 + rr;
                int nl = (wv & 1) * 32 + ni * 16 + r;
                Sp[ml * 64 + nl] = acc[mi][ni][rr];
            }
}

// ---- proj, XCD-clustered 1D grid (192 blocks) ----------------------------------------
__global__ __launch_bounds__(256) void mfma_proj(const unsigned short* __restrict__ Abf,
                                                 const unsigned short* __restrict__ Bbf,
                                                 const float* __restrict__ bias,
                                                 float* __restrict__ outp) {
    __shared__ __align__(16) unsigned short LB[3 * 8192];
    const int xcd = blockIdx.x & 7;
    const int q = xcd * 24 + (blockIdx.x >> 3); // 0..191
    const int tm = (q & 15) * 64;
    const int tn = (q >> 4) * 64;
    f32x4 acc[2][2] = {};
    gemm_core(Abf + (size_t)tm * Cn, Bbf + (size_t)tn * Cn, Cn, 12, LB, acc);

    const int wv = threadIdx.x >> 6, lane = threadIdx.x & 63;
    const int kq = lane >> 4, r = lane & 15;
    #pragma unroll
    for (int mi = 0; mi < 2; ++mi)
        #pragma unroll
        for (int ni = 0; ni < 2; ++ni)
            #pragma unroll
            for (int rr = 0; rr < 4; ++rr) {
                int mm = tm + (wv >> 1) * 32 + mi * 16 + kq * 4 + rr;
                int nn = tn + (wv & 1) * 32 + ni * 16 + r;
                outp[(size_t)mm * Cn + nn] = acc[mi][ni][rr] + bias[nn];
            }
}

// ---- DPP selection: ONE token per wave; XCD-clustered; top-8 via 8-round wave-max
// EXTRACTION (replaces Batcher sort + 6 butterfly merges + 64-ballot recovery):
// exact (value desc, global idx asc) incl. duplicates — per-lane argmax keeps lowest
// reg; wave_min over packed (reg*64+lane) = lowest global index. ~20 fewer live VGPRs
// (no key/pk/t arrays; topi is wave-uniform -> SGPRs) under the (256,8) 64-VGPR cap ---
__global__ __launch_bounds__(256, 8) void dpp_kernel(const float* __restrict__ S,
                                                     const float* __restrict__ khat,
                                                     const float* __restrict__ vh,
                                                     unsigned short* __restrict__ yb) {
    const int xcd = blockIdx.x & 7;
    const int vb = blockIdx.x >> 3;            // 0..383
    const int bh = xcd * 3 + (vb >> 7);
    const int iblk = vb & 127;
    const int w = threadIdx.x >> 6;
    const int lane = threadIdx.x & 63;
    const int i = iblk * 4 + w;                // token for this wave

    __shared__ float KshW[4][9][68];   //  9792 B
    __shared__ float VshW[4][9][64];   //  9216 B
    __shared__ float Gsh[4][81];       //  1296 B
    __shared__ float qdsh[4][9];       //   144 B  -> 20448 B total (8 blocks/CU)
    const float* Sbh = S + (size_t)bh * 147456;
    const float* kh = khat + (size_t)bh * Tn * HS;
    const float* vbase = vh + (size_t)bh * Tn * HS;

    const int t8 = i >> 6;
    const int tribase = t8 * (t8 + 1) / 2;
    const int rloc = (i & 63) * 64;

    float sv[8];
    #pragma unroll
    for (int rr = 0; rr < 8; ++rr) {
        sv[rr] = -INFINITY;
        if (rr <= t8) {
            int j = rr * 64 + lane;
            float s = Sbh[(size_t)(tribase + rr) * 4096 + rloc + lane];
            sv[rr] = (j <= i) ? s : -INFINITY;
        }
    }
    // qd0 = S[i][i] loaded directly (same addr all lanes -> broadcast)
    const float qd0 = Sbh[(size_t)(tribase + t8) * 4096 + rloc + (i & 63)];

    // ---- top-8 (value, index) via 8-round wave-max extraction ------------------------
    float pm;                  // per-lane max over remaining sv
    int pr;                    // its reg (lowest on within-lane ties -> lowest idx)
    pm = sv[0]; pr = 0;
    #pragma unroll
    for (int r = 1; r < 8; ++r) {
        bool g = sv[r] > pm;
        pm = g ? sv[r] : pm;
        pr = g ? r : pr;
    }
    int topi[8];               // wave-uniform (readlane results) -> SGPRs
    float myqd = qd0;          // this lane's qdsh staging value
    #pragma unroll
    for (int p = 0; p < 8; ++p) {
        const float m = wave_max(pm);
        const int cand = (pm == m) ? (pr * 64 + lane) : 0x7fffffff;
        const int widx = wave_min_i32(cand);       // lowest global idx among ties
        topi[p] = widx;
        if (lane == p + 1) myqd = m;               // qdsh slot p+1
        if (p < 7) {
            const int wl = widx & 63, wr = widx >> 6;   // wave-uniform
            const bool own = (lane == wl);
            #pragma unroll
            for (int r = 0; r < 8; ++r)
                if (r == wr) sv[r] = own ? -INFINITY : sv[r];
            pm = sv[0]; pr = 0;
            #pragma unroll
            for (int r = 1; r < 8; ++r) {
                bool g = sv[r] > pm;
                pm = g ? sv[r] : pm;
                pr = g ? r : pr;
            }
        }
    }
    // -inf padding rounds (i<7) yield in-range don't-care indices: vmask never selects
    // slots >= n_cand, staged rows feed only invalid combos, qdsh slot = -inf as before.

    // stage K/V rows (ctx = w; single-wave produce/consume, no barrier needed)
    #pragma unroll
    for (int a = 0; a < 9; ++a) {
        int t = (a == 0) ? i : topi[a - 1];
        KshW[w][a][lane] = kh[(size_t)t * HS + lane];
        VshW[w][a][lane] = vbase[(size_t)t * HS + lane];
    }
    if (lane < 9) qdsh[w][lane] = myqd;

    // gram (lanes 0..44)
    if (lane < 45) {
        const int a = PA[lane], b = PB[lane];
        const float4* rka = (const float4*)&KshW[w][a][0];
        const float4* rkb = (const float4*)&KshW[w][b][0];
        float acc = 0.f;
        #pragma unroll
        for (int t = 0; t < 16; ++t) {
            float4 fa = rka[t], fb = rkb[t];
            acc += fa.x * fb.x; acc += fa.y * fb.y;
            acc += fa.z * fb.z; acc += fa.w * fb.w;
        }
        Gsh[w][a * 9 + b] = acc;
        Gsh[w][b * 9 + a] = acc;
    }

    // combos (lanes 0..35)
    const int sl0c = (lane < NCOMB) ? C_SL0[lane] : -1;
    const int sl1c = (lane < NCOMB) ? C_SL1[lane] : -1;
    float score = -INFINITY;
    int ca = 0, cb = 0, sdim = 1;
    {
        const int n_cand = (i + 1 < MTOP) ? (i + 1) : MTOP;
        int vmask = 0;
        #pragma unroll
        for (int s = 0; s < MTOP; ++s)
            if (s < n_cand && topi[s] != i) vmask |= (1 << s);

        if (lane < NCOMB) {
            sdim = (sl1c < 0) ? 1 : 2;
            ca = sl0c + 1;
            cb = (sl1c < 0) ? 0 : sl1c + 1;
            bool valid = ((vmask >> sl0c) & 1);
            if (sdim == 2) valid = valid && ((vmask >> sl1c) & 1);
            float G00 = Gsh[w][0];
            float Gaa = Gsh[w][ca * 9 + ca];
            float G0a = Gsh[w][ca];
            float det;
            if (sdim == 1) {
                det = G00 * Gaa - G0a * G0a;
            } else {
                float G0b = Gsh[w][cb];
                float Gab = Gsh[w][ca * 9 + cb];
                float Gbb = Gsh[w][cb * 9 + cb];
                det = G00 * (Gaa * Gbb - Gab * Gab)
                    - G0a * (G0a * Gbb - Gab * G0b)
                    + G0b * (G0a * Gab - Gaa * G0b);
            }
            score = valid ? (logf(det + 1e-6f) / (float)(sdim + 1)) : NEGV;
        }
    }

    // softmax over scores: DPP reductions (VALU pipe)
    const float mxv = wave_max(score);
    const float ee = (lane < NCOMB) ? expf(score - mxv) : 0.f;
    const float sumv = wave_sum(ee);

    // per-lane prob-folded attention weights
    float pwx = 0.f, pwy = 0.f, pwz = 0.f;
    if (lane < NCOMB) {
        float prob = ee / sumv;
        float d0 = qdsh[w][0]  * 0.125f;
        float d1 = qdsh[w][ca] * 0.125f;
        float d2 = (sdim == 2) ? qdsh[w][cb] * 0.125f : -INFINITY;
        float m2 = fmaxf(fmaxf(d0, d1), d2);
        float e0 = expf(d0 - m2), e1 = expf(d1 - m2);
        float e2 = (sdim == 2) ? expf(d2 - m2) : 0.f;
        float inv = prob / (e0 + e1 + e2);
        pwx = e0 * inv; pwy = e1 * inv; pwz = e2 * inv;
    }

    // coefficient collapse via DPP sums: y = c0*V0 + sum_s cs[s]*V[s+1]
    const float c0 = wave_sum(pwx);
    float cs[8];
    #pragma unroll
    for (int s = 0; s < 8; ++s) {
        float contrib = ((sl0c == s) ? pwy : 0.f) + ((sl1c == s) ? pwz : 0.f);
        cs[s] = wave_sum(contrib);
    }

    // y (9 LDS b32 reads)
    {
        const bool hasValid = (mxv > -1e29f);
        const float v0 = VshW[w][0][lane];
        float y = v0;
        if (hasValid) {
            y = c0 * v0;
            #pragma unroll
            for (int s = 0; s < 8; ++s)
                y += cs[s] * VshW[w][s + 1][lane];
        }
        const int bb = bh / Hn, h = bh % Hn;
        yb[((size_t)(bb * Tn + i)) * Cn + h * HS + lane] = bf_rne(y);
    }
}

extern "C" void kernel_launch(void* const* d_in, const int* in_sizes, int n_in,
                              void* d_out, int out_size, void* d_ws, size_t ws_size,
                              hipStream_t stream) {
    const float* x      = (const float*)d_in[0];
    const float* W_attn = (const float*)d_in[1];
    const float* b_attn = (const float*)d_in[2];
    const float* W_proj = (const float*)d_in[3];
    const float* b_proj = (const float*)d_in[4];
    float* out = (float*)d_out;

    char* ws = (char*)d_ws;
    float* vh            = (float*)(ws);                          //  0        3 MB
    unsigned short* qcat = (unsigned short*)(ws + 3145728);       //  3 MB     9 MB
    unsigned short* kcat = (unsigned short*)(ws + 12582912);      // 12 MB     9 MB
    unsigned short* xcat = (unsigned short*)(ws + 22020096);      // 21 MB     4.5 MB (dead after qkv)
    unsigned short* Wcat = (unsigned short*)(ws + 26738688);      // 25.5 MB  10.125 MB (dead after qkv)
    float* S             = (float*)(ws + 26738688);               // overlays Wcat, 13.5 MB
    unsigned short* ybf  = xcat;                                  // overlays xcat after qkv
    unsigned short* Wpbf = (unsigned short*)(ws + 40894464);      // 39 MB     1.125 MB
    float* khat          = (float*)(ws + 44040192);               // 42 MB     3 MB -> 45 MB total

    // 1) all conversions in one launch (4 elems/thread)
    conv_all<<<dim3((NX + NW + NP) / 4 / 256), 256, 0, stream>>>(
        x, W_attn, W_proj, xcat, Wcat, Wpbf);

    // 2) fused qkv, 64x64 tiles, XCD-clustered (576 blocks, 3/CU); k-part also -> khat
    mfma_qkv<<<dim3(576), 256, 0, stream>>>(xcat, Wcat, b_attn, qcat, kcat, khat, vh);

    // 3) S = qcat @ kcat^T, XCD-clustered (3 bh per XCD)
    mfma_sim<<<dim3(864), 256, 0, stream>>>(qcat, kcat, S);

    // 4) dpp, XCD-clustered, extraction-based top-8
    dpp_kernel<<<dim3(3072), 256, 0, stream>>>(S, khat, vh, ybf);

    // 5) out = y @ Wp^T + bias, XCD-clustered
    mfma_proj<<<dim3(192), 256, 0, stream>>>(ybf, Wpbf, b_proj, out);
}